// Round 4
// baseline (2941.571 us; speedup 1.0000x reference)
//
#include <hip/hip_runtime.h>

#define NN 40960
#define NE 655360
#define ET (NE + NN)        // 696320 edges incl self-loops
#define D 128
#define NG 16
#define PL 33280            // params per layer (floats): Wl,Wr,bl,br,att,b

typedef unsigned int u32;
typedef unsigned short u16;
typedef long long i64;

__device__ __forceinline__ float bf2f(u16 v){ return __uint_as_float(((u32)v)<<16); }
__device__ __forceinline__ u16 f2bf(float f){
  u32 u = __float_as_uint(f);
  return (u16)((u + 0x7FFFu + ((u>>16)&1u)) >> 16);
}
__device__ __forceinline__ u32 encf(float f){
  u32 u = __float_as_uint(f);
  return u ^ ((u>>31) ? 0xFFFFFFFFu : 0x80000000u);
}
__device__ __forceinline__ float decf(u32 u){
  return __uint_as_float((u>>31) ? (u ^ 0x80000000u) : ~u);
}
// index fetch, dual int64/int32, clamped to [0,bound)
__device__ __forceinline__ int geti(const void* p, long long i, int f64, int bound){
  long long v = f64 ? ((const i64*)p)[i] : (long long)((const int*)p)[i];
  int x = (int)v;
  return (x < 0) ? 0 : ((x >= bound) ? bound-1 : x);
}
// dual-mode output store
__device__ __forceinline__ void stf(void* p, long long i, float v, int isbf){
  if (isbf) ((u16*)p)[i] = f2bf(v); else ((float*)p)[i] = v;
}

__global__ void k_zero_out32(float* __restrict__ o, int n){
  int i = blockIdx.x*256 + threadIdx.x;
  if (i < n) o[i] = 0.f;
}

// flags[0]: edge_index is int64; flags[1]: floats are bf16
__global__ void k_detect(const void* __restrict__ ei, const void* __restrict__ x, int* __restrict__ flags){
  __shared__ int nz, cnt;
  if (threadIdx.x == 0){ nz = 0; cnt = 0; }
  __syncthreads();
  if (((const int*)ei)[2*threadIdx.x + 1] != 0) atomicAdd(&nz, 1);
  if (threadIdx.x < 128){
    u16 v = ((const u16*)x)[2*threadIdx.x];
    int ex = (v >> 7) & 0xFF;
    if (ex >= 100 && ex <= 140) atomicAdd(&cnt, 1);
  }
  __syncthreads();
  if (threadIdx.x == 0){
    flags[0] = (nz == 0) ? 1 : 0;
    flags[1] = (cnt >= 64) ? 1 : 0;
  }
}

// convert float input (f32 or bf16) -> f32 workspace
__global__ void k_cvt(const void* __restrict__ src, float* __restrict__ dst, int n, const int* __restrict__ flags){
  int i = blockIdx.x*256 + threadIdx.x;
  if (i >= n) return;
  dst[i] = flags[1] ? bf2f(((const u16*)src)[i]) : ((const float*)src)[i];
}

// one block per node; 128 threads = output cols; X row loads are wave-uniform (scalar)
__global__ __launch_bounds__(128) void k_gemm(const float* __restrict__ X, const float* __restrict__ pr,
                                              float* __restrict__ xl, float* __restrict__ xr)
{
  int n = blockIdx.x, c = threadIdx.x;
  const float* xrow = X + (size_t)n*D;
  const float* Wl = pr;
  const float* Wr = pr + 16384;
  float al = pr[32768 + c], ar = pr[32896 + c];
  #pragma unroll 4
  for (int k = 0; k < D; ++k){
    float xv = xrow[k];
    al = fmaf(xv, Wl[k*D + c], al);
    ar = fmaf(xv, Wr[k*D + c], ar);
  }
  xl[(size_t)n*D + c] = al;
  xr[(size_t)n*D + c] = ar;
}

__global__ void k_init(float* __restrict__ hout, float* __restrict__ denom, u32* __restrict__ emax){
  int i = blockIdx.x*256 + threadIdx.x;
  if (i < NN*D) hout[i] = 0.f;
  if (i < NN*4){ denom[i] = 0.f; emax[i] = 0x007FFFFFu; }  // enc(-inf)
}

// one thread per (edge, head)
__global__ void k_logits(const float* __restrict__ xl, const float* __restrict__ xr,
    const void* __restrict__ ei, const float* __restrict__ pr,
    float* __restrict__ elog, u32* __restrict__ emax, const int* __restrict__ flags)
{
  int t = blockIdx.x*256 + threadIdx.x;
  if (t >= ET*4) return;
  int e = t >> 2, h = t & 3;
  int f = flags[0];
  int s, dd;
  if (e < NE){ s = geti(ei, e, f, NN); dd = geti(ei, (long long)NE + e, f, NN); }
  else { s = dd = e - NE; }
  const float* att = pr + 33024 + h*32;
  float acc = 0.f;
  #pragma unroll 8
  for (int c = 0; c < 32; ++c){
    int ch = h*32 + c;
    float m = xl[(size_t)s*D + ch] + xr[(size_t)dd*D + ch];
    m = (m > 0.f) ? m : 0.2f*m;
    acc = fmaf(m, att[c], acc);
  }
  elog[t] = acc;
  atomicMax(&emax[dd*4 + h], encf(acc));
}

__global__ void k_exp(const void* __restrict__ ei, float* __restrict__ elog,
                      const u32* __restrict__ emax, float* __restrict__ denom,
                      const int* __restrict__ flags){
  int t = blockIdx.x*256 + threadIdx.x;
  if (t >= ET*4) return;
  int e = t >> 2, h = t & 3;
  int dd = (e < NE) ? geti(ei, (long long)NE + e, flags[0], NN) : e - NE;
  float mx = decf(emax[dd*4 + h]);
  float ex = __expf(fminf(elog[t] - mx, 30.f));
  elog[t] = ex;
  unsafeAtomicAdd(&denom[dd*4 + h], ex);
}

// one wave per edge; lane covers channels lane and lane+64
__global__ __launch_bounds__(256) void k_agg(const float* __restrict__ xl, const void* __restrict__ ei,
    const float* __restrict__ elog, const float* __restrict__ denom,
    float* __restrict__ hout, const int* __restrict__ flags)
{
  int e = blockIdx.x*4 + (threadIdx.x >> 6);
  int lane = threadIdx.x & 63;
  int f = flags[0];
  int s, dd;
  if (e < NE){ s = geti(ei, e, f, NN); dd = geti(ei, (long long)NE + e, f, NN); }
  else { s = dd = e - NE; }
  int h1 = lane >> 5, h2 = 2 + (lane >> 5);
  float a1 = elog[(size_t)e*4 + h1] / fmaxf(denom[(size_t)dd*4 + h1], 1e-20f);
  float a2 = elog[(size_t)e*4 + h2] / fmaxf(denom[(size_t)dd*4 + h2], 1e-20f);
  int c1 = lane, c2 = lane + 64;
  unsafeAtomicAdd(&hout[(size_t)dd*D + c1], a1 * xl[(size_t)s*D + c1]);
  unsafeAtomicAdd(&hout[(size_t)dd*D + c2], a2 * xl[(size_t)s*D + c2]);
}

__global__ void k_bias_relu(float* __restrict__ hx, const float* __restrict__ pr){
  int i = blockIdx.x*256 + threadIdx.x;
  if (i < NN*D) hx[i] = fmaxf(hx[i] + pr[33152 + (i & 127)], 0.f);
}

__global__ void k_counts(const void* __restrict__ batch, u32* __restrict__ cnt, const int* __restrict__ flags){
  int i = blockIdx.x*256 + threadIdx.x;
  if (i < NN) atomicAdd(&cnt[geti(batch, i, flags[0], NG)], 1u);
}

__global__ void k_final(const float* __restrict__ hout, const float* __restrict__ pr,
    const void* __restrict__ batch, void* __restrict__ out, float* __restrict__ pool,
    const int* __restrict__ flags){
  int i = blockIdx.x*256 + threadIdx.x;
  if (i >= NN*D) return;
  int c = i & 127, n = i >> 7;
  float v = hout[i] + pr[33152 + c];
  stf(out, (long long)NG*D + i, v, flags[1]);      // h after pooled
  unsafeAtomicAdd(&pool[geti(batch, n, flags[0], NG)*D + c], v);
}

__global__ void k_pool_fin(const float* __restrict__ pool, const u32* __restrict__ cnt,
                           void* __restrict__ out, const int* __restrict__ flags){
  int i = blockIdx.x*256 + threadIdx.x;
  if (i < NG*D) stf(out, i, pool[i] / fmaxf((float)cnt[i >> 7], 1.f), flags[1]);
}

extern "C" void kernel_launch(void* const* d_in, const int* in_sizes, int n_in,
                              void* d_out, int out_size, void* d_ws, size_t ws_size,
                              hipStream_t stream) {
  const void* x     = d_in[0];
  const void* ei    = d_in[1];
  const void* batch = d_in[2];

  const long long n_ws = (long long)NN*D*3 + (long long)ET*4 + (long long)NN*4*2
                       + NG*D + NG + 3*PL + 8;
  if (ws_size < (size_t)n_ws*4 + 64) return;  // should not happen (verified ws >= 75MB)

  float* ws    = (float*)d_ws;
  float* xf    = ws;                              // NN*D (reused as hout)
  float* xl    = xf + (size_t)NN*D;
  float* xr    = xl + (size_t)NN*D;
  float* elog  = xr + (size_t)NN*D;               // ET*4
  float* denom = elog + (size_t)ET*4;             // NN*4
  u32*  emax   = (u32*)(denom + (size_t)NN*4);    // NN*4
  float* pool  = (float*)(emax + (size_t)NN*4);   // NG*D
  u32*  cnt    = (u32*)(pool + NG*D);             // NG
  float* prm   = (float*)(cnt + NG);              // 3*PL
  int*  flags  = (int*)(prm + 3*PL);              // 2
  float* hout  = xf;

  k_detect<<<1, 256, 0, stream>>>(ei, x, flags);
  k_cvt<<<(NN*D)/256, 256, 0, stream>>>(x, xf, NN*D, flags);
  k_zero_out32<<<9, 256, 0, stream>>>(pool, NG*D + NG);  // pool then cnt contiguous

  // convert all params to f32: per layer layout Wl[16384] Wr[16384] bl[128] br[128] att[128] b[128]
  for (int l = 0; l < 3; ++l){
    float* p = prm + l*PL;
    k_cvt<<<64, 256, 0, stream>>>(d_in[3+6*l+0], p,         16384, flags); // Wl
    k_cvt<<<64, 256, 0, stream>>>(d_in[3+6*l+2], p+16384,   16384, flags); // Wr
    k_cvt<<<1, 256, 0, stream>>>(d_in[3+6*l+1],  p+32768,   128, flags);   // bl
    k_cvt<<<1, 256, 0, stream>>>(d_in[3+6*l+3],  p+32896,   128, flags);   // br
    k_cvt<<<1, 256, 0, stream>>>(d_in[3+6*l+4],  p+33024,   128, flags);   // att
    k_cvt<<<1, 256, 0, stream>>>(d_in[3+6*l+5],  p+33152,   128, flags);   // b
  }

  for (int l = 0; l < 3; ++l){
    const float* p = prm + l*PL;
    k_gemm<<<NN, 128, 0, stream>>>(xf, p, xl, xr);
    k_init<<<(NN*D)/256, 256, 0, stream>>>(hout, denom, emax);
    k_logits<<<(ET*4)/256, 256, 0, stream>>>(xl, xr, ei, p, elog, emax, flags);
    k_exp<<<(ET*4)/256, 256, 0, stream>>>(ei, elog, emax, denom, flags);
    k_agg<<<ET/4, 256, 0, stream>>>(xl, ei, elog, denom, hout, flags);

    if (l < 2){
      k_bias_relu<<<(NN*D)/256, 256, 0, stream>>>(hout, p);
    } else {
      k_counts<<<NN/256, 256, 0, stream>>>(batch, cnt, flags);
      k_final<<<(NN*D)/256, 256, 0, stream>>>(hout, p, batch, d_out, pool, flags);
      k_pool_fin<<<8, 256, 0, stream>>>(pool, cnt, d_out, flags);
    }
  }
}

// Round 5
// 1984.060 us; speedup vs baseline: 1.4826x; 1.4826x over previous
//
#include <hip/hip_runtime.h>

#define NN 40960
#define NE 655360
#define ET (NE + NN)        // 696320 edges incl self-loops
#define D 128
#define NG 16
#define PL 33280            // params per layer (floats): Wl,Wr,bl,br,att,b

typedef unsigned int u32;
typedef unsigned short u16;
typedef long long i64;

__device__ __forceinline__ float bf2f(u16 v){ return __uint_as_float(((u32)v)<<16); }
__device__ __forceinline__ u16 f2bf(float f){
  u32 u = __float_as_uint(f);
  return (u16)((u + 0x7FFFu + ((u>>16)&1u)) >> 16);
}
// index fetch, dual int64/int32, clamped to [0,bound)
__device__ __forceinline__ int geti(const void* p, long long i, int f64, int bound){
  long long v = f64 ? ((const i64*)p)[i] : (long long)((const int*)p)[i];
  int x = (int)v;
  return (x < 0) ? 0 : ((x >= bound) ? bound-1 : x);
}
__device__ __forceinline__ void stf(void* p, long long i, float v, int isbf){
  if (isbf) ((u16*)p)[i] = f2bf(v); else ((float*)p)[i] = v;
}
__device__ __forceinline__ float rdf(const void* p, int i, int isbf){
  return isbf ? bf2f(((const u16*)p)[i]) : ((const float*)p)[i];
}

__global__ void k_zero_out32(float* __restrict__ o, int n){
  int i = blockIdx.x*256 + threadIdx.x;
  if (i < n) o[i] = 0.f;
}
__global__ void k_zero_u32(u32* __restrict__ o, int n){
  int i = blockIdx.x*256 + threadIdx.x;
  if (i < n) o[i] = 0u;
}

// flags[0]: indices are int64 ; flags[1]: floats are bf16
__global__ void k_detect(const void* __restrict__ ei, const void* __restrict__ x, int* __restrict__ flags){
  __shared__ int nz, cnt;
  if (threadIdx.x == 0){ nz = 0; cnt = 0; }
  __syncthreads();
  if (((const int*)ei)[2*threadIdx.x + 1] != 0) atomicAdd(&nz, 1);
  if (threadIdx.x < 128){
    u16 v = ((const u16*)x)[2*threadIdx.x];
    int ex = (v >> 7) & 0xFF;
    if (ex >= 100 && ex <= 140) atomicAdd(&cnt, 1);
  }
  __syncthreads();
  if (threadIdx.x == 0){
    flags[0] = (nz == 0) ? 1 : 0;
    flags[1] = (cnt >= 64) ? 1 : 0;
  }
}

__global__ void k_cvt(const void* __restrict__ src, float* __restrict__ dst, int n, const int* __restrict__ flags){
  int i = blockIdx.x*256 + threadIdx.x;
  if (i >= n) return;
  dst[i] = rdf(src, i, flags[1]);
}

// pack one layer's params into prm: Wl[16384] Wr[16384] bl br att b (128 each)
__global__ void k_cvtp(const void* Wl, const void* bl, const void* Wr, const void* br,
                       const void* att, const void* b, float* __restrict__ p, const int* __restrict__ flags){
  int i = blockIdx.x*256 + threadIdx.x;
  if (i >= PL) return;
  int isbf = flags[1];
  float v;
  if      (i < 16384) v = rdf(Wl, i, isbf);
  else if (i < 32768) v = rdf(Wr, i - 16384, isbf);
  else if (i < 32896) v = rdf(bl, i - 32768, isbf);
  else if (i < 33024) v = rdf(br, i - 32896, isbf);
  else if (i < 33152) v = rdf(att, i - 33024, isbf);
  else                v = rdf(b, i - 33152, isbf);
  p[i] = v;
}

// ---------- CSR build (by dst, self-loops appended) ----------
__global__ void k_hist(const void* __restrict__ ei, u32* __restrict__ cursor, const int* __restrict__ flags){
  int e = blockIdx.x*256 + threadIdx.x;
  if (e >= ET) return;
  int dd = (e < NE) ? geti(ei, (long long)NE + e, flags[0], NN) : e - NE;
  atomicAdd(&cursor[dd], 1u);
}

// single block, 1024 threads, chunk of 40 each: exclusive scan of cursor -> offs, cursor
__global__ __launch_bounds__(1024) void k_scan(u32* __restrict__ cursor, u32* __restrict__ offs){
  __shared__ u32 part[1024];
  int t = threadIdx.x;
  int base = t * 40;
  u32 s = 0;
  #pragma unroll 4
  for (int i = 0; i < 40; ++i) s += cursor[base + i];
  part[t] = s;
  __syncthreads();
  for (int off = 1; off < 1024; off <<= 1){
    u32 v = (t >= off) ? part[t - off] : 0u;
    __syncthreads();
    part[t] += v;
    __syncthreads();
  }
  u32 run = (t == 0) ? 0u : part[t - 1];
  for (int i = 0; i < 40; ++i){
    u32 d = cursor[base + i];
    offs[base + i] = run;
    cursor[base + i] = run;
    run += d;
  }
  if (t == 1023) offs[NN] = run;   // == ET
}

__global__ void k_scatter(const void* __restrict__ ei, u32* __restrict__ cursor,
                          u32* __restrict__ csr, const int* __restrict__ flags){
  int e = blockIdx.x*256 + threadIdx.x;
  if (e >= ET) return;
  int f = flags[0];
  int s, dd;
  if (e < NE){ s = geti(ei, e, f, NN); dd = geti(ei, (long long)NE + e, f, NN); }
  else { s = dd = e - NE; }
  u32 pos = atomicAdd(&cursor[dd], 1u);
  csr[pos] = (u32)s;
}

// graph boundaries in sorted batch_vec
__global__ void k_bounds(const void* __restrict__ batch, u32* __restrict__ bnd, const int* __restrict__ flags){
  int g = threadIdx.x;
  if (g > NG) return;
  if (g == NG){ bnd[NG] = NN; return; }
  int f = flags[0];
  int lo = 0, hi = NN;
  while (lo < hi){
    int mid = (lo + hi) >> 1;
    if (geti(batch, mid, f, NG) < g) lo = mid + 1; else hi = mid;
  }
  bnd[g] = (u32)lo;
}

// ---------- GEMM: xl = X@Wl+bl, xr = X@Wr+br. 64 rows/block, W staged packed in LDS ----------
__global__ __launch_bounds__(256) void k_gemm(const float* __restrict__ X, const float* __restrict__ pr,
                                              float* __restrict__ xl, float* __restrict__ xr)
{
  __shared__ float2 wp[128*64];   // 64KB: wp[k*64+cl] = (Wl[k][col], Wr[k][col])
  int tid = threadIdx.x;
  int row0 = blockIdx.x * 64;
  int cl = tid & 63;
  int rs = tid >> 6;              // 0..3, wave-uniform
  const float* Wl = pr;
  const float* Wr = pr + 16384;
  for (int half = 0; half < 2; ++half){
    for (int i = tid; i < 128*64; i += 256){
      int k = i >> 6, c = (i & 63) + half*64;
      wp[i] = make_float2(Wl[k*128 + c], Wr[k*128 + c]);
    }
    __syncthreads();
    int col = half*64 + cl;
    float bll = pr[32768 + col], brr = pr[32896 + col];
    for (int rg = 0; rg < 8; ++rg){
      int r0 = row0 + rg*8 + rs;                 // rows r0, r0+4
      const float4* x0 = (const float4*)(X + (size_t)r0 * D);
      const float4* x1 = (const float4*)(X + (size_t)(r0 + 4) * D);
      float a0l = bll, a0r = brr, a1l = bll, a1r = brr;
      for (int k4 = 0; k4 < 32; ++k4){
        float4 xv0 = x0[k4];
        float4 xv1 = x1[k4];
        const float2* wrow = wp + (k4*4)*64 + cl;
        float2 w0 = wrow[0], w1 = wrow[64], w2 = wrow[128], w3 = wrow[192];
        a0l = fmaf(xv0.x, w0.x, a0l); a0r = fmaf(xv0.x, w0.y, a0r);
        a1l = fmaf(xv1.x, w0.x, a1l); a1r = fmaf(xv1.x, w0.y, a1r);
        a0l = fmaf(xv0.y, w1.x, a0l); a0r = fmaf(xv0.y, w1.y, a0r);
        a1l = fmaf(xv1.y, w1.x, a1l); a1r = fmaf(xv1.y, w1.y, a1r);
        a0l = fmaf(xv0.z, w2.x, a0l); a0r = fmaf(xv0.z, w2.y, a0r);
        a1l = fmaf(xv1.z, w2.x, a1l); a1r = fmaf(xv1.z, w2.y, a1r);
        a0l = fmaf(xv0.w, w3.x, a0l); a0r = fmaf(xv0.w, w3.y, a0r);
        a1l = fmaf(xv1.w, w3.x, a1l); a1r = fmaf(xv1.w, w3.y, a1r);
      }
      xl[(size_t)r0*D + col] = a0l;       xr[(size_t)r0*D + col] = a0r;
      xl[(size_t)(r0+4)*D + col] = a1l;   xr[(size_t)(r0+4)*D + col] = a1r;
    }
    __syncthreads();
  }
}

// ---------- fused attention per node: one wave per node, two passes over in-edges ----------
__global__ __launch_bounds__(256) void k_node(const float* __restrict__ xl, const float* __restrict__ xr,
    const u32* __restrict__ offs, const u32* __restrict__ csr, const float* __restrict__ pr,
    float* __restrict__ elog, float* __restrict__ hnew, void* __restrict__ out,
    const int* __restrict__ flags, int last)
{
  int node = blockIdx.x*4 + (threadIdx.x >> 6);
  int lane = threadIdx.x & 63;
  int c1 = lane, c2 = lane + 64;
  int hs = lane >> 5;              // head sub-index within pair
  float xr1 = xr[(size_t)node*D + c1];
  float xr2 = xr[(size_t)node*D + c2];
  float att1 = pr[33024 + c1], att2 = pr[33024 + c2];
  u32 j0 = offs[node], j1 = offs[node + 1];

  float mx1 = -1e30f, mx2 = -1e30f, s1 = 0.f, s2 = 0.f;
  for (u32 j = j0; j < j1; ++j){
    int s = (int)csr[j];
    float m1 = xl[(size_t)s*D + c1] + xr1;
    float m2 = xl[(size_t)s*D + c2] + xr2;
    m1 = (m1 > 0.f) ? m1 : 0.2f*m1;
    m2 = (m2 > 0.f) ? m2 : 0.2f*m2;
    float v1 = m1 * att1, v2 = m2 * att2;
    #pragma unroll
    for (int off = 16; off > 0; off >>= 1){
      v1 += __shfl_xor(v1, off, 32);
      v2 += __shfl_xor(v2, off, 32);
    }
    if ((lane & 31) == 0){
      elog[(size_t)j*4 + hs]     = v1;
      elog[(size_t)j*4 + 2 + hs] = v2;
    }
    float n1 = fmaxf(mx1, v1);
    s1 = fmaf(s1, __expf(mx1 - n1), __expf(v1 - n1)); mx1 = n1;
    float n2 = fmaxf(mx2, v2);
    s2 = fmaf(s2, __expf(mx2 - n2), __expf(v2 - n2)); mx2 = n2;
  }
  float inv1 = 1.0f / fmaxf(s1, 1e-30f);
  float inv2 = 1.0f / fmaxf(s2, 1e-30f);

  float acc1 = 0.f, acc2 = 0.f;
  for (u32 j = j0; j < j1; ++j){
    int s = (int)csr[j];
    float a1 = __expf(elog[(size_t)j*4 + hs]     - mx1) * inv1;
    float a2 = __expf(elog[(size_t)j*4 + 2 + hs] - mx2) * inv2;
    acc1 += a1 * xl[(size_t)s*D + c1];
    acc2 += a2 * xl[(size_t)s*D + c2];
  }
  float v1 = acc1 + pr[33152 + c1];
  float v2 = acc2 + pr[33152 + c2];
  if (!last){
    hnew[(size_t)node*D + c1] = fmaxf(v1, 0.f);
    hnew[(size_t)node*D + c2] = fmaxf(v2, 0.f);
  } else {
    hnew[(size_t)node*D + c1] = v1;
    hnew[(size_t)node*D + c2] = v2;
    int isbf = flags[1];
    stf(out, (long long)NG*D + (long long)node*D + c1, v1, isbf);
    stf(out, (long long)NG*D + (long long)node*D + c2, v2, isbf);
  }
}

// mean-pool per graph from sorted boundaries (no atomics)
__global__ __launch_bounds__(256) void k_pool(const float* __restrict__ h, const u32* __restrict__ bnd,
                                              void* __restrict__ out, const int* __restrict__ flags){
  __shared__ float red[256];
  int g = blockIdx.x, t = threadIdx.x;
  int ch = t & 127, ro = t >> 7;
  u32 b0 = bnd[g], b1 = bnd[g + 1];
  float acc = 0.f;
  for (u32 r = b0 + ro; r < b1; r += 2) acc += h[(size_t)r*D + ch];
  red[t] = acc;
  __syncthreads();
  if (t < 128){
    float v = red[t] + red[t + 128];
    float c = (float)(b1 - b0);
    stf(out, (long long)g*D + t, v / fmaxf(c, 1.f), flags[1]);
  }
}

extern "C" void kernel_launch(void* const* d_in, const int* in_sizes, int n_in,
                              void* d_out, int out_size, void* d_ws, size_t ws_size,
                              hipStream_t stream) {
  const void* x     = d_in[0];
  const void* ei    = d_in[1];
  const void* batch = d_in[2];

  // float section
  const long long nf = (long long)NN*D*3 + (long long)ET*4 + 3*PL;
  // u32 section
  const long long nu = (NN + 1) + NN + ET + (NG + 1) + 2;
  if (ws_size < (size_t)(nf + nu)*4 + 256){
    k_zero_out32<<<(out_size + 255)/256, 256, 0, stream>>>((float*)d_out, out_size/2); // diagnostic
    return;
  }

  float* ws    = (float*)d_ws;
  float* xf    = ws;                               // NN*D (recycled as h output each layer)
  float* xl    = xf + (size_t)NN*D;
  float* xr    = xl + (size_t)NN*D;
  float* elog  = xr + (size_t)NN*D;                // ET*4
  float* prm   = elog + (size_t)ET*4;              // 3*PL
  u32*  offs   = (u32*)(prm + 3*PL);               // NN+1
  u32*  cursor = offs + (NN + 1);                  // NN
  u32*  csr    = cursor + NN;                      // ET
  u32*  bnd    = csr + ET;                         // NG+1
  int*  flags  = (int*)(bnd + (NG + 1));           // 2

  k_detect<<<1, 256, 0, stream>>>(ei, x, flags);
  k_cvt<<<(NN*D)/256, 256, 0, stream>>>(x, xf, NN*D, flags);
  for (int l = 0; l < 3; ++l)
    k_cvtp<<<(PL + 255)/256, 256, 0, stream>>>(d_in[3+6*l+0], d_in[3+6*l+1], d_in[3+6*l+2],
                                               d_in[3+6*l+3], d_in[3+6*l+4], d_in[3+6*l+5],
                                               prm + (size_t)l*PL, flags);

  // CSR build (once, reused all 3 layers)
  k_zero_u32<<<NN/256, 256, 0, stream>>>(cursor, NN);
  k_hist<<<ET/256, 256, 0, stream>>>(ei, cursor, flags);
  k_scan<<<1, 1024, 0, stream>>>(cursor, offs);
  k_scatter<<<ET/256, 256, 0, stream>>>(ei, cursor, csr, flags);
  k_bounds<<<1, 32, 0, stream>>>(batch, bnd, flags);

  for (int l = 0; l < 3; ++l){
    const float* p = prm + (size_t)l*PL;
    k_gemm<<<NN/64, 256, 0, stream>>>(xf, p, xl, xr);
    k_node<<<NN/4, 256, 0, stream>>>(xl, xr, offs, csr, p, elog, xf, d_out, flags, l == 2);
  }
  k_pool<<<NG, 256, 0, stream>>>(xf, bnd, d_out, flags);
}

// Round 6
// 646.316 us; speedup vs baseline: 4.5513x; 3.0698x over previous
//
#include <hip/hip_runtime.h>

#define NN 40960
#define NE 655360
#define ET (NE + NN)        // 696320 edges incl self-loops
#define D 128
#define NG 16
#define PL 33280            // params per layer (floats): WF[32768], bf[256], att[128], b[128]

typedef unsigned int u32;
typedef unsigned short u16;
typedef long long i64;

__device__ __forceinline__ float bf2f(u16 v){ return __uint_as_float(((u32)v)<<16); }
__device__ __forceinline__ u16 f2bf(float f){
  u32 u = __float_as_uint(f);
  return (u16)((u + 0x7FFFu + ((u>>16)&1u)) >> 16);
}
__device__ __forceinline__ int geti(const void* p, long long i, int f64, int bound){
  long long v = f64 ? ((const i64*)p)[i] : (long long)((const int*)p)[i];
  int x = (int)v;
  return (x < 0) ? 0 : ((x >= bound) ? bound-1 : x);
}
__device__ __forceinline__ void stf(void* p, long long i, float v, int isbf){
  if (isbf) ((u16*)p)[i] = f2bf(v); else ((float*)p)[i] = v;
}
__device__ __forceinline__ float rdf(const void* p, int i, int isbf){
  return isbf ? bf2f(((const u16*)p)[i]) : ((const float*)p)[i];
}

__global__ void k_zero_out32(float* __restrict__ o, int n){
  int i = blockIdx.x*256 + threadIdx.x;
  if (i < n) o[i] = 0.f;
}
__global__ void k_zero_u32(u32* __restrict__ o, int n){
  int i = blockIdx.x*256 + threadIdx.x;
  if (i < n) o[i] = 0u;
}

// flags[0]: indices are int64 ; flags[1]: floats are bf16
__global__ void k_detect(const void* __restrict__ ei, const void* __restrict__ x, int* __restrict__ flags){
  __shared__ int nz, cnt;
  if (threadIdx.x == 0){ nz = 0; cnt = 0; }
  __syncthreads();
  if (((const int*)ei)[2*threadIdx.x + 1] != 0) atomicAdd(&nz, 1);
  if (threadIdx.x < 128){
    u16 v = ((const u16*)x)[2*threadIdx.x];
    int ex = (v >> 7) & 0xFF;
    if (ex >= 100 && ex <= 140) atomicAdd(&cnt, 1);
  }
  __syncthreads();
  if (threadIdx.x == 0){
    flags[0] = (nz == 0) ? 1 : 0;
    flags[1] = (cnt >= 64) ? 1 : 0;
  }
}

__global__ void k_cvt(const void* __restrict__ src, float* __restrict__ dst, int n, const int* __restrict__ flags){
  int i = blockIdx.x*256 + threadIdx.x;
  if (i >= n) return;
  dst[i] = rdf(src, i, flags[1]);
}

// fused param pack: WF[k*256+gc] = (gc<128 ? Wl[k][gc] : Wr[k][gc-128]); bf[256]=bl|br; att; b
__global__ void k_cvtp(const void* Wl, const void* bl, const void* Wr, const void* br,
                       const void* att, const void* b, float* __restrict__ p, const int* __restrict__ flags){
  int i = blockIdx.x*256 + threadIdx.x;
  if (i >= PL) return;
  int isbf = flags[1];
  float v;
  if (i < 32768){
    int k = i >> 8, gc = i & 255;
    v = (gc < 128) ? rdf(Wl, k*128 + gc, isbf) : rdf(Wr, k*128 + gc - 128, isbf);
  }
  else if (i < 33024){ int gc = i - 32768; v = (gc < 128) ? rdf(bl, gc, isbf) : rdf(br, gc - 128, isbf); }
  else if (i < 33152) v = rdf(att, i - 33024, isbf);
  else                v = rdf(b, i - 33152, isbf);
  p[i] = v;
}

// ---------- CSR build (by dst, self-loops appended) ----------
__global__ void k_hist(const void* __restrict__ ei, u32* __restrict__ cursor, const int* __restrict__ flags){
  int e = blockIdx.x*256 + threadIdx.x;
  if (e >= ET) return;
  int dd = (e < NE) ? geti(ei, (long long)NE + e, flags[0], NN) : e - NE;
  atomicAdd(&cursor[dd], 1u);
}

__global__ __launch_bounds__(1024) void k_scan(u32* __restrict__ cursor, u32* __restrict__ offs){
  __shared__ u32 part[1024];
  int t = threadIdx.x;
  int base = t * 40;
  u32 s = 0;
  #pragma unroll 4
  for (int i = 0; i < 40; ++i) s += cursor[base + i];
  part[t] = s;
  __syncthreads();
  for (int off = 1; off < 1024; off <<= 1){
    u32 v = (t >= off) ? part[t - off] : 0u;
    __syncthreads();
    part[t] += v;
    __syncthreads();
  }
  u32 run = (t == 0) ? 0u : part[t - 1];
  for (int i = 0; i < 40; ++i){
    u32 d = cursor[base + i];
    offs[base + i] = run;
    cursor[base + i] = run;
    run += d;
  }
  if (t == 1023) offs[NN] = run;
}

__global__ void k_scatter(const void* __restrict__ ei, u32* __restrict__ cursor,
                          u32* __restrict__ csr, const int* __restrict__ flags){
  int e = blockIdx.x*256 + threadIdx.x;
  if (e >= ET) return;
  int f = flags[0];
  int s, dd;
  if (e < NE){ s = geti(ei, e, f, NN); dd = geti(ei, (long long)NE + e, f, NN); }
  else { s = dd = e - NE; }
  u32 pos = atomicAdd(&cursor[dd], 1u);
  csr[pos] = (u32)s;
}

__global__ void k_bounds(const void* __restrict__ batch, u32* __restrict__ bnd, const int* __restrict__ flags){
  int g = threadIdx.x;
  if (g > NG) return;
  if (g == NG){ bnd[NG] = NN; return; }
  int f = flags[0];
  int lo = 0, hi = NN;
  while (lo < hi){
    int mid = (lo + hi) >> 1;
    if (geti(batch, mid, f, NG) < g) lo = mid + 1; else hi = mid;
  }
  bnd[g] = (u32)lo;
}

// ---------- GEMM: 64 rows x 64 cols per block, K=128 one-shot, 4x4 register tile ----------
__global__ __launch_bounds__(256) void k_gemm(const float* __restrict__ X, const float* __restrict__ pr,
                                              float* __restrict__ xl, float* __restrict__ xr)
{
  __shared__ float Xs[128][64];   // [k][row]   32 KB
  __shared__ float Ws[128][64];   // [k][col]   32 KB
  int tid = threadIdx.x;
  int row0 = blockIdx.x * 64;
  int bc0  = blockIdx.y * 64;     // global col base in [0,256)

  const float4* Xg = (const float4*)(X + (size_t)row0 * D);
  #pragma unroll
  for (int i = 0; i < 8; ++i){
    int idx = tid + i*256;
    int row = idx >> 5, k4 = idx & 31;
    float4 v = Xg[(size_t)row*32 + k4];
    Xs[k4*4+0][row] = v.x;
    Xs[k4*4+1][row] = v.y;
    Xs[k4*4+2][row] = v.z;
    Xs[k4*4+3][row] = v.w;
  }
  #pragma unroll
  for (int i = 0; i < 8; ++i){
    int idx = tid + i*256;
    int k = idx >> 4, c4 = idx & 15;
    float4 v = *(const float4*)(pr + (size_t)k*256 + bc0 + c4*4);
    *(float4*)&Ws[k][c4*4] = v;
  }
  __syncthreads();

  int ty = tid >> 4, tx = tid & 15;
  int r = ty*4, c = tx*4;
  float4 bias = *(const float4*)(pr + 32768 + bc0 + c);
  float acc[4][4];
  #pragma unroll
  for (int i = 0; i < 4; ++i){
    acc[i][0] = bias.x; acc[i][1] = bias.y; acc[i][2] = bias.z; acc[i][3] = bias.w;
  }
  #pragma unroll 4
  for (int k = 0; k < 128; ++k){
    float4 a = *(const float4*)&Xs[k][r];
    float4 b = *(const float4*)&Ws[k][c];
    acc[0][0] = fmaf(a.x, b.x, acc[0][0]); acc[0][1] = fmaf(a.x, b.y, acc[0][1]);
    acc[0][2] = fmaf(a.x, b.z, acc[0][2]); acc[0][3] = fmaf(a.x, b.w, acc[0][3]);
    acc[1][0] = fmaf(a.y, b.x, acc[1][0]); acc[1][1] = fmaf(a.y, b.y, acc[1][1]);
    acc[1][2] = fmaf(a.y, b.z, acc[1][2]); acc[1][3] = fmaf(a.y, b.w, acc[1][3]);
    acc[2][0] = fmaf(a.z, b.x, acc[2][0]); acc[2][1] = fmaf(a.z, b.y, acc[2][1]);
    acc[2][2] = fmaf(a.z, b.z, acc[2][2]); acc[2][3] = fmaf(a.z, b.w, acc[2][3]);
    acc[3][0] = fmaf(a.w, b.x, acc[3][0]); acc[3][1] = fmaf(a.w, b.y, acc[3][1]);
    acc[3][2] = fmaf(a.w, b.z, acc[3][2]); acc[3][3] = fmaf(a.w, b.w, acc[3][3]);
  }
  float* base = (bc0 < 128) ? xl : xr;
  int co = (bc0 < 128) ? bc0 + c : bc0 - 128 + c;
  #pragma unroll
  for (int i = 0; i < 4; ++i)
    *(float4*)(base + (size_t)(row0 + r + i)*D + co) =
        make_float4(acc[i][0], acc[i][1], acc[i][2], acc[i][3]);
}

// ---------- fused attention per node: one wave per node, SINGLE pass (online softmax) ----------
__global__ __launch_bounds__(256) void k_node(const float* __restrict__ xl, const float* __restrict__ xr,
    const u32* __restrict__ offs, const u32* __restrict__ csr, const float* __restrict__ pr,
    float* __restrict__ hnew, void* __restrict__ out, const int* __restrict__ flags, int last)
{
  int node = blockIdx.x*4 + (threadIdx.x >> 6);
  int lane = threadIdx.x & 63;
  int c1 = lane, c2 = lane + 64;
  float xr1 = xr[(size_t)node*D + c1];
  float xr2 = xr[(size_t)node*D + c2];
  float att1 = pr[33024 + c1], att2 = pr[33024 + c2];
  u32 j0 = offs[node], j1 = offs[node + 1];

  float mx1 = -1e30f, mx2 = -1e30f, s1 = 0.f, s2 = 0.f, acc1 = 0.f, acc2 = 0.f;
  for (u32 j = j0; j < j1; ++j){
    int s = (int)csr[j];
    float g1 = xl[(size_t)s*D + c1];
    float g2 = xl[(size_t)s*D + c2];
    float m1 = g1 + xr1; m1 = (m1 > 0.f) ? m1 : 0.2f*m1;
    float m2 = g2 + xr2; m2 = (m2 > 0.f) ? m2 : 0.2f*m2;
    float v1 = m1 * att1, v2 = m2 * att2;
    #pragma unroll
    for (int off = 16; off > 0; off >>= 1){
      v1 += __shfl_xor(v1, off, 32);
      v2 += __shfl_xor(v2, off, 32);
    }
    float n1 = fmaxf(mx1, v1);
    float eo1 = __expf(mx1 - n1), en1 = __expf(v1 - n1);
    s1 = fmaf(s1, eo1, en1);
    acc1 = fmaf(acc1, eo1, en1 * g1);
    mx1 = n1;
    float n2 = fmaxf(mx2, v2);
    float eo2 = __expf(mx2 - n2), en2 = __expf(v2 - n2);
    s2 = fmaf(s2, eo2, en2);
    acc2 = fmaf(acc2, eo2, en2 * g2);
    mx2 = n2;
  }
  float v1 = acc1 / fmaxf(s1, 1e-30f) + pr[33152 + c1];
  float v2 = acc2 / fmaxf(s2, 1e-30f) + pr[33152 + c2];
  if (!last){
    hnew[(size_t)node*D + c1] = fmaxf(v1, 0.f);
    hnew[(size_t)node*D + c2] = fmaxf(v2, 0.f);
  } else {
    hnew[(size_t)node*D + c1] = v1;
    hnew[(size_t)node*D + c2] = v2;
    int isbf = flags[1];
    stf(out, (long long)NG*D + (long long)node*D + c1, v1, isbf);
    stf(out, (long long)NG*D + (long long)node*D + c2, v2, isbf);
  }
}

// ---------- two-stage mean pool ----------
__global__ __launch_bounds__(256) void k_pool1(const float* __restrict__ h, const u32* __restrict__ bnd,
                                               float* __restrict__ pool){
  int g = blockIdx.x >> 6, sl = blockIdx.x & 63;
  int ch = threadIdx.x & 127, ro = threadIdx.x >> 7;
  u32 b0 = bnd[g], b1 = bnd[g + 1];
  float acc = 0.f;
  for (u32 r = b0 + sl*2 + ro; r < b1; r += 128) acc += h[(size_t)r*D + ch];
  unsafeAtomicAdd(&pool[g*D + ch], acc);
}

__global__ void k_pool2(const float* __restrict__ pool, const u32* __restrict__ bnd,
                        void* __restrict__ out, const int* __restrict__ flags){
  int i = blockIdx.x*256 + threadIdx.x;
  if (i >= NG*D) return;
  int g = i >> 7;
  float c = (float)(bnd[g + 1] - bnd[g]);
  stf(out, i, pool[i] / fmaxf(c, 1.f), flags[1]);
}

extern "C" void kernel_launch(void* const* d_in, const int* in_sizes, int n_in,
                              void* d_out, int out_size, void* d_ws, size_t ws_size,
                              hipStream_t stream) {
  const void* x     = d_in[0];
  const void* ei    = d_in[1];
  const void* batch = d_in[2];

  const long long nf = (long long)NN*D*3 + 3*PL + NG*D;
  const long long nu = (NN + 1) + NN + ET + (NG + 1) + 2;
  if (ws_size < (size_t)(nf + nu)*4 + 256) return;

  float* ws    = (float*)d_ws;
  float* xf    = ws;                               // NN*D (recycled as h each layer)
  float* xl    = xf + (size_t)NN*D;
  float* xr    = xl + (size_t)NN*D;
  float* prm   = xr + (size_t)NN*D;                // 3*PL
  float* pool  = prm + 3*PL;                       // NG*D
  u32*  offs   = (u32*)(pool + NG*D);              // NN+1
  u32*  cursor = offs + (NN + 1);                  // NN
  u32*  csr    = cursor + NN;                      // ET
  u32*  bnd    = csr + ET;                         // NG+1
  int*  flags  = (int*)(bnd + (NG + 1));           // 2

  k_detect<<<1, 256, 0, stream>>>(ei, x, flags);
  k_cvt<<<(NN*D)/256, 256, 0, stream>>>(x, xf, NN*D, flags);
  for (int l = 0; l < 3; ++l)
    k_cvtp<<<(PL + 255)/256, 256, 0, stream>>>(d_in[3+6*l+0], d_in[3+6*l+1], d_in[3+6*l+2],
                                               d_in[3+6*l+3], d_in[3+6*l+4], d_in[3+6*l+5],
                                               prm + (size_t)l*PL, flags);

  k_zero_u32<<<NN/256, 256, 0, stream>>>(cursor, NN);
  k_hist<<<ET/256, 256, 0, stream>>>(ei, cursor, flags);
  k_scan<<<1, 1024, 0, stream>>>(cursor, offs);
  k_scatter<<<ET/256, 256, 0, stream>>>(ei, cursor, csr, flags);
  k_bounds<<<1, 32, 0, stream>>>(batch, bnd, flags);
  k_zero_out32<<<8, 256, 0, stream>>>(pool, NG*D);

  for (int l = 0; l < 3; ++l){
    const float* p = prm + (size_t)l*PL;
    k_gemm<<<dim3(NN/64, 4), 256, 0, stream>>>(xf, p, xl, xr);
    k_node<<<NN/4, 256, 0, stream>>>(xl, xr, offs, csr, p, xf, d_out, flags, l == 2);
  }
  k_pool1<<<NG*64, 256, 0, stream>>>(xf, bnd, pool);
  k_pool2<<<8, 256, 0, stream>>>(pool, bnd, d_out, flags);
}